// Round 1
// baseline (195.070 us; speedup 1.0000x reference)
//
#include <hip/hip_runtime.h>
#include <math.h>

constexpr int S = 2048;
constexpr int D = 512;
constexpr int S_PER_WAVE = 16;
constexpr int WAVES_PER_BLOCK = 4;

// Kernel 1: y[b,s] = dot(x[b,s,:], W) + bias, written into d_out (used as scratch).
// One wave per 16 consecutive s. Lane l owns W[l*4..l*4+4) and W[256+l*4..+4).
__global__ __launch_bounds__(256) void dot_kernel(const float* __restrict__ x,
                                                  const float* __restrict__ W,
                                                  const float* __restrict__ bias,
                                                  float* __restrict__ y) {
    const int lane = threadIdx.x & 63;
    const int wave = threadIdx.x >> 6;
    const int g = blockIdx.x * WAVES_PER_BLOCK + wave;   // group id
    const int b = g >> 7;            // 2048/16 = 128 groups per row
    const int sg = g & 127;
    const int s0 = sg * S_PER_WAVE;

    const float* xp = x + ((long long)b * S + s0) * D;
    const float4 w0 = *(const float4*)(W + lane * 4);
    const float4 w1 = *(const float4*)(W + 256 + lane * 4);
    const float bb = bias[0];

    float res = 0.0f;
#pragma unroll 4
    for (int i = 0; i < S_PER_WAVE; ++i) {
        const float* row = xp + (long long)i * D;
        const float4 a0 = *(const float4*)(row + lane * 4);
        const float4 a1 = *(const float4*)(row + 256 + lane * 4);
        float p = a0.x * w0.x + a0.y * w0.y + a0.z * w0.z + a0.w * w0.w
                + a1.x * w1.x + a1.y * w1.y + a1.z * w1.z + a1.w * w1.w;
#pragma unroll
        for (int off = 32; off >= 1; off >>= 1) p += __shfl_xor(p, off);
        if (lane == i) res = p + bb;   // lane i keeps s0+i's result
    }
    if (lane < S_PER_WAVE) y[(long long)b * S + s0 + lane] = res;
}

// Kernel 2: per-row masked min/max normalize + stable partition (zeros first).
// Reads y from d_out (all loads complete before first barrier), writes d_out permuted.
__global__ __launch_bounds__(256) void finalize_kernel(float* __restrict__ out,
                                                       const int* __restrict__ mask) {
    const int b = blockIdx.x;
    const int t = threadIdx.x;   // 256 threads, 8 elements each

    const float* yr = out + (long long)b * S;
    const int* mr = mask + (long long)b * S;

    const float4 v0 = ((const float4*)yr)[t * 2];
    const float4 v1 = ((const float4*)yr)[t * 2 + 1];
    const int4 m0 = ((const int4*)mr)[t * 2];
    const int4 m1 = ((const int4*)mr)[t * 2 + 1];
    float v[8] = {v0.x, v0.y, v0.z, v0.w, v1.x, v1.y, v1.z, v1.w};
    int   m[8] = {m0.x, m0.y, m0.z, m0.w, m1.x, m1.y, m1.z, m1.w};

    float mn = INFINITY, mx = -INFINITY;
    int c = 0;
#pragma unroll
    for (int i = 0; i < 8; ++i) {
        if (m[i] == 0) { mn = fminf(mn, v[i]); mx = fmaxf(mx, v[i]); }
        else ++c;
    }

    __shared__ float smn[256];
    __shared__ float smx[256];
    __shared__ int sc[256];
    smn[t] = mn; smx[t] = mx; sc[t] = c;
    __syncthreads();   // also guarantees all y-loads above are done before any write below

    // tree reduce min/max into [0]
    for (int off = 128; off >= 1; off >>= 1) {
        if (t < off) {
            smn[t] = fminf(smn[t], smn[t + off]);
            smx[t] = fmaxf(smx[t], smx[t + off]);
        }
        __syncthreads();
    }
    const float gmn = smn[0];
    const float gmx = smx[0];

    // Hillis-Steele inclusive scan of per-thread one-counts
    for (int off = 1; off < 256; off <<= 1) {
        const int add = (t >= off) ? sc[t - off] : 0;
        __syncthreads();
        sc[t] += add;
        __syncthreads();
    }
    const int total_ones = sc[255];
    const int ones_before_thread = sc[t] - c;   // exclusive
    const int zeros_total = S - total_ones;
    const float denom = gmx - gmn;

    float* orow = out + (long long)b * S;
    int run = ones_before_thread;
#pragma unroll
    for (int i = 0; i < 8; ++i) {
        const int s = t * 8 + i;
        if (m[i]) {
            orow[zeros_total + run] = v[i];   // masked: raw value, after all zeros
            ++run;
        } else {
            orow[s - run] = (v[i] - gmn) / denom;   // unmasked: normalized, stable order
        }
    }
}

extern "C" void kernel_launch(void* const* d_in, const int* in_sizes, int n_in,
                              void* d_out, int out_size, void* d_ws, size_t ws_size,
                              hipStream_t stream) {
    const float* x    = (const float*)d_in[0];
    const int*   mask = (const int*)d_in[1];
    const float* W    = (const float*)d_in[2];
    const float* bias = (const float*)d_in[3];
    float* out = (float*)d_out;

    const int B = out_size / S;                       // 256
    const int total_groups = B * (S / S_PER_WAVE);    // 32768 waves
    const int blocks = total_groups / WAVES_PER_BLOCK; // 8192

    dot_kernel<<<blocks, 256, 0, stream>>>(x, W, bias, out);
    finalize_kernel<<<B, 256, 0, stream>>>(out, mask);
}

// Round 3
// 177.307 us; speedup vs baseline: 1.1002x; 1.1002x over previous
//
#include <hip/hip_runtime.h>
#include <math.h>

constexpr int S = 2048;
constexpr int D = 512;
constexpr int S_PER_WAVE = 16;     // rows per wave
constexpr int WAVES_PER_BLOCK = 4;

typedef float floatx4 __attribute__((ext_vector_type(4)));

// Kernel 1: y[b,s] = dot(x[b,s,:], W) + bias, into d_out (scratch).
// Each wave = 4 groups of 16 lanes; each group computes one row per iteration.
// Lane (grp, subl) holds W float4 fragments at indices subl + 16k, k=0..7.
__global__ __launch_bounds__(256) void dot_kernel(const float* __restrict__ x,
                                                  const float* __restrict__ W,
                                                  const float* __restrict__ bias,
                                                  float* __restrict__ y) {
    const int lane = threadIdx.x & 63;
    const int subl = lane & 15;
    const int grp  = lane >> 4;
    const int wave = threadIdx.x >> 6;
    const int g = blockIdx.x * WAVES_PER_BLOCK + wave;   // wave id
    const int b  = g >> 7;           // 2048/16 = 128 waves per row
    const int sg = g & 127;
    const int s0 = sg * S_PER_WAVE;

    const float* xp = x + ((long long)b * S + s0) * D;

    floatx4 w[8];
#pragma unroll
    for (int k = 0; k < 8; ++k)
        w[k] = *(const floatx4*)(W + subl * 4 + k * 64);
    const float bb = bias[0];

    float res = 0.0f;
#pragma unroll
    for (int i = 0; i < 4; ++i) {            // 4 iterations x 4 rows = 16 rows
        const float* row = xp + (long long)(i * 4 + grp) * D;
        float p = 0.0f;
#pragma unroll
        for (int k = 0; k < 8; ++k) {
            const floatx4 a = __builtin_nontemporal_load((const floatx4*)(row + subl * 4 + k * 64));
            p += a.x * w[k].x + a.y * w[k].y + a.z * w[k].z + a.w * w[k].w;
        }
        // reduce within the 16-lane group (xor masks < 16 stay in-group)
        p += __shfl_xor(p, 1);
        p += __shfl_xor(p, 2);
        p += __shfl_xor(p, 4);
        p += __shfl_xor(p, 8);
        if (subl == i) res = p + bb;         // lane (grp, i) keeps row i*4+grp
    }
    // 16 contiguous dwords (64 B), one segment
    if (subl < 4) y[(long long)b * S + s0 + subl * 4 + grp] = res;
}

// Kernel 2: per-row masked min/max normalize + stable partition (zeros first).
// In-place on d_out; __syncthreads drains all loads (vmcnt 0) before any store.
__global__ __launch_bounds__(256) void finalize_kernel(float* __restrict__ out,
                                                       const int* __restrict__ mask) {
    const int b = blockIdx.x;
    const int t = threadIdx.x;       // 256 threads, 8 elements each
    const int lane = t & 63;
    const int wv = t >> 6;           // 4 waves

    const float* yr = out + (long long)b * S;
    const int*   mr = mask + (long long)b * S;

    const float4 v0 = ((const float4*)yr)[t * 2];
    const float4 v1 = ((const float4*)yr)[t * 2 + 1];
    const int4   m0 = ((const int4*)mr)[t * 2];
    const int4   m1 = ((const int4*)mr)[t * 2 + 1];
    float v[8] = {v0.x, v0.y, v0.z, v0.w, v1.x, v1.y, v1.z, v1.w};
    int   m[8] = {m0.x, m0.y, m0.z, m0.w, m1.x, m1.y, m1.z, m1.w};

    float mn = INFINITY, mx = -INFINITY;
    int c = 0;
#pragma unroll
    for (int i = 0; i < 8; ++i) {
        if (m[i] == 0) { mn = fminf(mn, v[i]); mx = fmaxf(mx, v[i]); }
        else ++c;
    }

    // wave-level min/max reduce + inclusive scan of c
    float wmn = mn, wmx = mx;
#pragma unroll
    for (int off = 32; off >= 1; off >>= 1) {
        wmn = fminf(wmn, __shfl_xor(wmn, off));
        wmx = fmaxf(wmx, __shfl_xor(wmx, off));
    }
    int incl = c;
#pragma unroll
    for (int off = 1; off < 64; off <<= 1) {
        const int n = __shfl_up(incl, off);
        if (lane >= off) incl += n;
    }

    __shared__ float smn[4];
    __shared__ float smx[4];
    __shared__ int   swc[4];
    if (lane == 63) { smn[wv] = wmn; smx[wv] = wmx; swc[wv] = incl; }
    __syncthreads();   // drains vmcnt(0): all y-loads complete before any store below

    float gmn = smn[0], gmx = smx[0];
    int total_ones = 0;
#pragma unroll
    for (int w = 1; w < 4; ++w) {
        gmn = fminf(gmn, smn[w]);
        gmx = fmaxf(gmx, smx[w]);
    }
#pragma unroll
    for (int w = 0; w < 4; ++w) total_ones += swc[w];

    int wave_off = 0;
#pragma unroll
    for (int w = 0; w < 4; ++w) if (w < wv) wave_off += swc[w];

    const int ones_before_thread = wave_off + incl - c;   // exclusive over elements
    const int zeros_total = S - total_ones;
    const float denom = gmx - gmn;

    float* orow = out + (long long)b * S;
    int run = ones_before_thread;
#pragma unroll
    for (int i = 0; i < 8; ++i) {
        const int s = t * 8 + i;
        if (m[i]) {
            orow[zeros_total + run] = v[i];               // masked: raw, after all zeros
            ++run;
        } else {
            orow[s - run] = (v[i] - gmn) / denom;         // unmasked: normalized, stable
        }
    }
}

extern "C" void kernel_launch(void* const* d_in, const int* in_sizes, int n_in,
                              void* d_out, int out_size, void* d_ws, size_t ws_size,
                              hipStream_t stream) {
    const float* x    = (const float*)d_in[0];
    const int*   mask = (const int*)d_in[1];
    const float* W    = (const float*)d_in[2];
    const float* bias = (const float*)d_in[3];
    float* out = (float*)d_out;

    const int B = out_size / S;                         // 256
    const int total_waves = B * (S / S_PER_WAVE);       // 32768
    const int blocks = total_waves / WAVES_PER_BLOCK;   // 8192

    dot_kernel<<<blocks, 256, 0, stream>>>(x, W, bias, out);
    finalize_kernel<<<B, 256, 0, stream>>>(out, mask);
}

// Round 4
// 162.298 us; speedup vs baseline: 1.2019x; 1.0925x over previous
//
#include <hip/hip_runtime.h>
#include <math.h>

constexpr int S = 2048;
constexpr int D = 512;

typedef float floatx4 __attribute__((ext_vector_type(4)));

// One block per row b. Phase 1: 64 groups of 16 lanes compute the 2048 dot
// products into LDS ys[]. Phase 2: block-wide masked min/max + stable
// partition scan + scatter to out. x is read once with NT loads.
__global__ __launch_bounds__(1024) void fused_kernel(const float* __restrict__ x,
                                                     const int* __restrict__ mask,
                                                     const float* __restrict__ W,
                                                     const float* __restrict__ bias,
                                                     float* __restrict__ out) {
    __shared__ float ys[S];        // 8 KB
    __shared__ float smn[16];
    __shared__ float smx[16];
    __shared__ int   swc[16];

    const int t = threadIdx.x;     // 0..1023
    const int lane16 = t & 15;
    const int gid = t >> 4;        // 0..63 (16-lane group id)
    const int b = blockIdx.x;

    const float* xb = x + (long long)b * S * D;

    floatx4 w[8];
#pragma unroll
    for (int k = 0; k < 8; ++k)
        w[k] = *(const floatx4*)(W + lane16 * 4 + k * 64);
    const float bb = bias[0];

    // ---- Phase 1: dot products. Group gid handles rows i*64+gid. ----
    for (int i = 0; i < 32; ++i) {
        const int s = i * 64 + gid;
        const float* row = xb + (long long)s * D;
        float p = 0.0f;
#pragma unroll
        for (int k = 0; k < 8; ++k) {
            const floatx4 a = __builtin_nontemporal_load((const floatx4*)(row + lane16 * 4 + k * 64));
            p += a.x * w[k].x + a.y * w[k].y + a.z * w[k].z + a.w * w[k].w;
        }
        p += __shfl_xor(p, 1);
        p += __shfl_xor(p, 2);
        p += __shfl_xor(p, 4);
        p += __shfl_xor(p, 8);
        if (lane16 == 0) ys[s] = p + bb;
    }
    __syncthreads();

    // ---- Phase 2: masked min/max + stable partition. 2 elements/thread. ----
    const int lane = t & 63;
    const int wv = t >> 6;         // 0..15

    const int2 mm = ((const int2*)(mask + (long long)b * S))[t];
    const float2 vv = ((const float2*)ys)[t];
    const float va = vv.x, vb = vv.y;

    int c = (mm.x != 0) + (mm.y != 0);
    float mn = INFINITY, mx = -INFINITY;
    if (mm.x == 0) { mn = va; mx = va; }
    if (mm.y == 0) { mn = fminf(mn, vb); mx = fmaxf(mx, vb); }

    float wmn = mn, wmx = mx;
#pragma unroll
    for (int off = 32; off >= 1; off >>= 1) {
        wmn = fminf(wmn, __shfl_xor(wmn, off));
        wmx = fmaxf(wmx, __shfl_xor(wmx, off));
    }
    int incl = c;
#pragma unroll
    for (int off = 1; off < 64; off <<= 1) {
        const int n = __shfl_up(incl, off);
        if (lane >= off) incl += n;
    }

    if (lane == 63) { smn[wv] = wmn; smx[wv] = wmx; swc[wv] = incl; }
    __syncthreads();

    float gmn = INFINITY, gmx = -INFINITY;
    int total_ones = 0, wave_off = 0;
#pragma unroll
    for (int w = 0; w < 16; ++w) {
        gmn = fminf(gmn, smn[w]);
        gmx = fmaxf(gmx, smx[w]);
        total_ones += swc[w];
        if (w < wv) wave_off += swc[w];
    }

    const int zeros_total = S - total_ones;
    const float denom = gmx - gmn;
    float* orow = out + (long long)b * S;

    int run = wave_off + incl - c;   // ones strictly before this thread's elems
    if (mm.x) { orow[zeros_total + run] = va; ++run; }
    else      { orow[2 * t - run] = (va - gmn) / denom; }
    if (mm.y) { orow[zeros_total + run] = vb; ++run; }
    else      { orow[2 * t + 1 - run] = (vb - gmn) / denom; }
}

extern "C" void kernel_launch(void* const* d_in, const int* in_sizes, int n_in,
                              void* d_out, int out_size, void* d_ws, size_t ws_size,
                              hipStream_t stream) {
    const float* x    = (const float*)d_in[0];
    const int*   mask = (const int*)d_in[1];
    const float* W    = (const float*)d_in[2];
    const float* bias = (const float*)d_in[3];
    float* out = (float*)d_out;

    const int B = out_size / S;    // 256 rows -> 256 blocks, 1 per CU
    fused_kernel<<<B, 1024, 0, stream>>>(x, mask, W, bias, out);
}